// Round 1
// baseline (2915.149 us; speedup 1.0000x reference)
//
#include <hip/hip_runtime.h>
#include <hip/hip_bf16.h>
#include <math.h>

// Problem constants (from reference): B=32, L=128, D=6, T=63, V=50000, E=C=128, H=256
#define NV 50000
#define NE 128
#define NC 128
#define NH 256
#define NB 32
#define NL 128
#define NT 63
#define G3 768   // 3*H

__device__ __forceinline__ float sigmoidf_(float x) { return 1.0f / (1.0f + expf(-x)); }

// ---------------------------------------------------------------------------
// Generic C[m][n] = sum_k A[m][k] * B[n][k] (+ bias[n]), K=128 fixed.
// Tile 64(M) x 128(N), 256 threads, thread tile 4x8.
// ---------------------------------------------------------------------------
__global__ __launch_bounds__(256) void gemm_bt_k128(
    const float* __restrict__ A, const float* __restrict__ Bm,
    const float* __restrict__ bias, float* __restrict__ Cm,
    int M, int N) {
  __shared__ __align__(16) float As[64 * 129];    // padded stride 129
  __shared__ __align__(16) float BsT[128 * 132];  // transposed, padded stride 132
  const int m0 = blockIdx.x * 64;
  const int n0 = blockIdx.y * 128;
  const int tid = threadIdx.x;

  // Load A tile (64x128), coalesced, zero-pad M tail.
#pragma unroll
  for (int i = 0; i < 32; ++i) {
    int e = tid + i * 256;
    int r = e >> 7, k = e & 127;
    int m = m0 + r;
    As[r * 129 + k] = (m < M) ? A[(size_t)m * 128 + k] : 0.0f;
  }
  // Load B tile (128x128) transposed into LDS.
#pragma unroll
  for (int i = 0; i < 64; ++i) {
    int e = tid + i * 256;
    int n = e >> 7, k = e & 127;
    BsT[k * 132 + n] = Bm[(size_t)(n0 + n) * 128 + k];
  }
  __syncthreads();

  const int tn = tid & 15;        // 16 n-groups of 8
  const int tm = tid >> 4;        // 16 m-groups of 4
  const int ml = tm * 4, nl = tn * 8;

  float acc[4][8];
#pragma unroll
  for (int i = 0; i < 4; ++i)
#pragma unroll
    for (int j = 0; j < 8; ++j) acc[i][j] = 0.0f;

#pragma unroll 4
  for (int k = 0; k < 128; ++k) {
    float a0 = As[(ml + 0) * 129 + k];
    float a1 = As[(ml + 1) * 129 + k];
    float a2 = As[(ml + 2) * 129 + k];
    float a3 = As[(ml + 3) * 129 + k];
    float4 b0 = *(const float4*)&BsT[k * 132 + nl];
    float4 b1 = *(const float4*)&BsT[k * 132 + nl + 4];
    const float bv[8] = {b0.x, b0.y, b0.z, b0.w, b1.x, b1.y, b1.z, b1.w};
#pragma unroll
    for (int j = 0; j < 8; ++j) {
      acc[0][j] = fmaf(a0, bv[j], acc[0][j]);
      acc[1][j] = fmaf(a1, bv[j], acc[1][j]);
      acc[2][j] = fmaf(a2, bv[j], acc[2][j]);
      acc[3][j] = fmaf(a3, bv[j], acc[3][j]);
    }
  }

  float bv[8];
#pragma unroll
  for (int j = 0; j < 8; ++j) bv[j] = bias ? bias[n0 + nl + j] : 0.0f;

#pragma unroll
  for (int i = 0; i < 4; ++i) {
    int m = m0 + ml + i;
    if (m < M) {
      float* crow = &Cm[(size_t)m * N + n0 + nl];
#pragma unroll
      for (int j = 0; j < 8; ++j) crow[j] = acc[i][j] + bv[j];
    }
  }
}

// ---------------------------------------------------------------------------
// Tree encode: per (b,l), heap-sum P[tok] over subtrees, + cnt*bc, max, relu.
// Block = one (b,l), 128 threads (one per channel c).
// ---------------------------------------------------------------------------
__global__ __launch_bounds__(128) void tree_encode(
    const int* __restrict__ tokens, const float* __restrict__ P,
    const float* __restrict__ bc, float* __restrict__ enc) {
  __shared__ int toks[NT];
  const int blk = blockIdx.x;  // b*L + l
  const int c = threadIdx.x;
  if (c < NT) toks[c] = tokens[(size_t)blk * NT + c];
  __syncthreads();

  float s[NT];
#pragma unroll
  for (int i = 0; i < NT; ++i) s[i] = P[(size_t)toks[i] * NC + c];
  // bottom-up heap accumulation: node i += children 2i+1, 2i+2
#pragma unroll
  for (int i = 30; i >= 0; --i) s[i] += s[2 * i + 1] + s[2 * i + 2];

  const float bcv = bc[c];
  float m = -1e30f;
#pragma unroll
  for (int i = 0; i < NT; ++i) {
    const float cnt = (i == 0) ? 63.0f
                    : (i < 3)  ? 31.0f
                    : (i < 7)  ? 15.0f
                    : (i < 15) ? 7.0f
                    : (i < 31) ? 3.0f
                               : 1.0f;
    m = fmaxf(m, s[i] + cnt * bcv);
  }
  enc[(size_t)blk * NC + c] = fmaxf(m, 0.0f);
}

// ---------------------------------------------------------------------------
// GRU scan: one block per (dir, batch row). 768 threads: thread j computes
// gh[j] = Whh[j,:] @ h each step; threads 0..255 then do gates + h update +
// running max. Output = max over t, written once at the end.
// GI = [2][B][L][768] precomputed gi + bih (bhh applied here, since the
// n-gate needs bhh_n inside r*(...)).
// ---------------------------------------------------------------------------
__global__ __launch_bounds__(768) void gru_scan(
    const float* __restrict__ GI,
    const float* __restrict__ Whh_f, const float* __restrict__ Whh_b,
    const float* __restrict__ bhh_f, const float* __restrict__ bhh_b,
    float* __restrict__ out) {
  const int dir = blockIdx.x >> 5;
  const int b = blockIdx.x & 31;
  const int tid = threadIdx.x;
  const float* __restrict__ W = dir ? Whh_b : Whh_f;
  const float* __restrict__ bhh = dir ? bhh_b : bhh_f;
  const float* __restrict__ gi_base =
      GI + ((size_t)dir * NB * NL + (size_t)b * NL) * G3;

  __shared__ __align__(16) float hs[NH];
  __shared__ float gh[G3];

  float br = 0.f, bz = 0.f, bn = 0.f, hmax = -1e30f;
  if (tid < NH) {
    hs[tid] = 0.0f;
    br = bhh[tid];
    bz = bhh[tid + NH];
    bn = bhh[tid + 2 * NH];
  }
  const float4* __restrict__ W4 = (const float4*)(W + (size_t)tid * NH);
  __syncthreads();

  for (int st = 0; st < NL; ++st) {
    const int t = dir ? (NL - 1 - st) : st;
    // phase 1: gh[j] = Whh[j,:] @ h
    float acc = 0.0f;
    const float4* h4 = (const float4*)hs;
#pragma unroll 8
    for (int k4 = 0; k4 < NH / 4; ++k4) {
      float4 w = W4[k4];
      float4 hv = h4[k4];
      acc = fmaf(w.x, hv.x, acc);
      acc = fmaf(w.y, hv.y, acc);
      acc = fmaf(w.z, hv.z, acc);
      acc = fmaf(w.w, hv.w, acc);
    }
    gh[tid] = acc;
    __syncthreads();
    // phase 2: gates + state update (threads 0..255)
    if (tid < NH) {
      const float* gi = gi_base + (size_t)t * G3;
      float r = sigmoidf_(gi[tid] + gh[tid] + br);
      float z = sigmoidf_(gi[tid + NH] + gh[tid + NH] + bz);
      float n = tanhf(gi[tid + 2 * NH] + r * (gh[tid + 2 * NH] + bn));
      float hnew = (1.0f - z) * n + z * hs[tid];
      hmax = fmaxf(hmax, hnew);
      hs[tid] = hnew;
    }
    __syncthreads();
  }
  if (tid < NH) out[(size_t)b * (2 * NH) + (size_t)dir * NH + tid] = hmax;
}

// ---------------------------------------------------------------------------
extern "C" void kernel_launch(void* const* d_in, const int* in_sizes, int n_in,
                              void* d_out, int out_size, void* d_ws, size_t ws_size,
                              hipStream_t stream) {
  const int*   tokens = (const int*)d_in[0];
  const float* emb    = (const float*)d_in[1];
  const float* Wc     = (const float*)d_in[2];
  const float* bc     = (const float*)d_in[3];
  const float* Wih_f  = (const float*)d_in[4];
  const float* Whh_f  = (const float*)d_in[5];
  const float* bih_f  = (const float*)d_in[6];
  const float* bhh_f  = (const float*)d_in[7];
  const float* Wih_b  = (const float*)d_in[8];
  const float* Whh_b  = (const float*)d_in[9];
  const float* bih_b  = (const float*)d_in[10];
  const float* bhh_b  = (const float*)d_in[11];
  float* out = (float*)d_out;

  // Workspace layout (f32): P[V*C] | enc[B*L*C] | GI[2*B*L*3H]  (~52.9 MB)
  float* P   = (float*)d_ws;
  float* enc = P + (size_t)NV * NC;
  float* GI  = enc + (size_t)NB * NL * NC;

  // 1) P = emb @ Wc^T   (V x C)
  gemm_bt_k128<<<dim3((NV + 63) / 64, NC / 128), dim3(256), 0, stream>>>(
      emb, Wc, nullptr, P, NV, NC);
  // 2) tree encode -> enc (B*L x C)
  tree_encode<<<dim3(NB * NL), dim3(128), 0, stream>>>(tokens, P, bc, enc);
  // 3) GI_f = enc @ Wih_f^T + bih_f ; GI_b likewise
  gemm_bt_k128<<<dim3(NB * NL / 64, G3 / 128), dim3(256), 0, stream>>>(
      enc, Wih_f, bih_f, GI, NB * NL, G3);
  gemm_bt_k128<<<dim3(NB * NL / 64, G3 / 128), dim3(256), 0, stream>>>(
      enc, Wih_b, bih_b, GI + (size_t)NB * NL * G3, NB * NL, G3);
  // 4) GRU scan, both directions + running max over t
  gru_scan<<<dim3(64), dim3(768), 0, stream>>>(
      GI, Whh_f, Whh_b, bhh_f, bhh_b, out);
}

// Round 2
// 355.329 us; speedup vs baseline: 8.2041x; 8.2041x over previous
//
#include <hip/hip_runtime.h>
#include <hip/hip_bf16.h>
#include <hip/hip_fp16.h>
#include <math.h>

// Problem constants: B=32, L=128, D=6, T=63, V=50000, E=C=128, H=256
#define NV 50000
#define NE 128
#define NC 128
#define NH 256
#define NB 32
#define NL 128
#define NT 63
#define G3 768   // 3*H

typedef _Float16 half2_t __attribute__((ext_vector_type(2)));

__device__ __forceinline__ float sigmoidf_(float x) { return 1.0f / (1.0f + expf(-x)); }

// dot2: c += a.x*b.x + a.y*b.y  (f16 inputs, f32 accumulate)
__device__ __forceinline__ float fdot2_(unsigned int a, unsigned int b, float c) {
#if __has_builtin(__builtin_amdgcn_fdot2)
  return __builtin_amdgcn_fdot2(__builtin_bit_cast(half2_t, a),
                                __builtin_bit_cast(half2_t, b), c, false);
#else
  half2_t ah = __builtin_bit_cast(half2_t, a);
  half2_t bh = __builtin_bit_cast(half2_t, b);
  return fmaf((float)ah[0], (float)bh[0], fmaf((float)ah[1], (float)bh[1], c));
#endif
}

// ---------------------------------------------------------------------------
// Generic C[m][n] = sum_k A[m][k] * B[n][k] (+ bias[n]), K=128 fixed.
// ---------------------------------------------------------------------------
__global__ __launch_bounds__(256) void gemm_bt_k128(
    const float* __restrict__ A, const float* __restrict__ Bm,
    const float* __restrict__ bias, float* __restrict__ Cm,
    int M, int N) {
  __shared__ __align__(16) float As[64 * 129];
  __shared__ __align__(16) float BsT[128 * 132];
  const int m0 = blockIdx.x * 64;
  const int n0 = blockIdx.y * 128;
  const int tid = threadIdx.x;

#pragma unroll
  for (int i = 0; i < 32; ++i) {
    int e = tid + i * 256;
    int r = e >> 7, k = e & 127;
    int m = m0 + r;
    As[r * 129 + k] = (m < M) ? A[(size_t)m * 128 + k] : 0.0f;
  }
#pragma unroll
  for (int i = 0; i < 64; ++i) {
    int e = tid + i * 256;
    int n = e >> 7, k = e & 127;
    BsT[k * 132 + n] = Bm[(size_t)(n0 + n) * 128 + k];
  }
  __syncthreads();

  const int tn = tid & 15;
  const int tm = tid >> 4;
  const int ml = tm * 4, nl = tn * 8;

  float acc[4][8];
#pragma unroll
  for (int i = 0; i < 4; ++i)
#pragma unroll
    for (int j = 0; j < 8; ++j) acc[i][j] = 0.0f;

#pragma unroll 4
  for (int k = 0; k < 128; ++k) {
    float a0 = As[(ml + 0) * 129 + k];
    float a1 = As[(ml + 1) * 129 + k];
    float a2 = As[(ml + 2) * 129 + k];
    float a3 = As[(ml + 3) * 129 + k];
    float4 b0 = *(const float4*)&BsT[k * 132 + nl];
    float4 b1 = *(const float4*)&BsT[k * 132 + nl + 4];
    const float bv[8] = {b0.x, b0.y, b0.z, b0.w, b1.x, b1.y, b1.z, b1.w};
#pragma unroll
    for (int j = 0; j < 8; ++j) {
      acc[0][j] = fmaf(a0, bv[j], acc[0][j]);
      acc[1][j] = fmaf(a1, bv[j], acc[1][j]);
      acc[2][j] = fmaf(a2, bv[j], acc[2][j]);
      acc[3][j] = fmaf(a3, bv[j], acc[3][j]);
    }
  }

  float bv[8];
#pragma unroll
  for (int j = 0; j < 8; ++j) bv[j] = bias ? bias[n0 + nl + j] : 0.0f;

#pragma unroll
  for (int i = 0; i < 4; ++i) {
    int m = m0 + ml + i;
    if (m < M) {
      float* crow = &Cm[(size_t)m * N + n0 + nl];
#pragma unroll
      for (int j = 0; j < 8; ++j) crow[j] = acc[i][j] + bv[j];
    }
  }
}

// ---------------------------------------------------------------------------
// Tree encode (unchanged): per (b,l), heap-sum P[tok], + cnt*bc, max, relu.
// ---------------------------------------------------------------------------
__global__ __launch_bounds__(128) void tree_encode(
    const int* __restrict__ tokens, const float* __restrict__ P,
    const float* __restrict__ bc, float* __restrict__ enc) {
  __shared__ int toks[NT];
  const int blk = blockIdx.x;
  const int c = threadIdx.x;
  if (c < NT) toks[c] = tokens[(size_t)blk * NT + c];
  __syncthreads();

  float s[NT];
#pragma unroll
  for (int i = 0; i < NT; ++i) s[i] = P[(size_t)toks[i] * NC + c];
#pragma unroll
  for (int i = 30; i >= 0; --i) s[i] += s[2 * i + 1] + s[2 * i + 2];

  const float bcv = bc[c];
  float m = -1e30f;
#pragma unroll
  for (int i = 0; i < NT; ++i) {
    const float cnt = (i == 0) ? 63.0f
                    : (i < 3)  ? 31.0f
                    : (i < 7)  ? 15.0f
                    : (i < 15) ? 7.0f
                    : (i < 31) ? 3.0f
                               : 1.0f;
    m = fmaxf(m, s[i] + cnt * bcv);
  }
  enc[(size_t)blk * NC + c] = fmaxf(m, 0.0f);
}

// ---------------------------------------------------------------------------
// Pack Whh (f32, [768][256]) -> f16 pairs ([2][768][128] uint).
// ---------------------------------------------------------------------------
__global__ __launch_bounds__(256) void conv_w_f16(
    const float* __restrict__ Wf, const float* __restrict__ Wb,
    unsigned int* __restrict__ out) {
  int i = blockIdx.x * 256 + threadIdx.x;   // pair index, [0, 768*128)
  if (i < G3 * (NH / 2)) {
    float2 a = ((const float2*)Wf)[i];
    __half2 ha = __floats2half2_rn(a.x, a.y);
    out[i] = *(unsigned int*)&ha;
    float2 b = ((const float2*)Wb)[i];
    __half2 hb = __floats2half2_rn(b.x, b.y);
    out[G3 * (NH / 2) + i] = *(unsigned int*)&hb;
  }
}

// ---------------------------------------------------------------------------
// GRU scan, W register-resident. One block per (dir, batch). 768 threads;
// thread j holds Whh row j as 128 packed-f16 dwords in VGPRs (loaded once).
// Per step: gh[j] = dot2(Wrow_j, h_f16_LDS); then threads<256 do gates +
// state update + running max. Output written once at the end.
// ---------------------------------------------------------------------------
__global__ __launch_bounds__(768, 3) void gru_scan_reg(
    const unsigned int* __restrict__ Wh16, const float* __restrict__ GI,
    const float* __restrict__ bhh_f, const float* __restrict__ bhh_b,
    float* __restrict__ out) {
  const int dir = blockIdx.x >> 5;
  const int b = blockIdx.x & 31;
  const int tid = threadIdx.x;

  __shared__ __align__(16) unsigned int h16p[NH / 2];  // h as packed f16 pairs
  __shared__ float gh[G3];

  // Preload this thread's Whh row into registers (one-time, 512B/thread).
  unsigned int w[128];
  {
    const uint4* wrow = (const uint4*)(Wh16 + ((size_t)dir * G3 + tid) * (NH / 2));
#pragma unroll
    for (int i = 0; i < 32; ++i) {
      uint4 v = wrow[i];
      w[4 * i + 0] = v.x; w[4 * i + 1] = v.y;
      w[4 * i + 2] = v.z; w[4 * i + 3] = v.w;
    }
  }

  const float* __restrict__ bhh = dir ? bhh_b : bhh_f;
  float br = 0.f, bz = 0.f, bn = 0.f, hreg = 0.f, hmax = -1e30f;
  if (tid < NH) {
    br = bhh[tid];
    bz = bhh[tid + NH];
    bn = bhh[tid + 2 * NH];
  }
  if (tid < NH / 2) h16p[tid] = 0u;
  const float* __restrict__ gi_base =
      GI + ((size_t)dir * NB * NL + (size_t)b * NL) * G3;
  __syncthreads();

  for (int st = 0; st < NL; ++st) {
    const int t = dir ? (NL - 1 - st) : st;
    // Issue GI loads early (independent of h) to hide L2 latency under dots.
    float gir = 0.f, giz = 0.f, gin = 0.f;
    if (tid < NH) {
      const float* gi = gi_base + (size_t)t * G3;
      gir = gi[tid];
      giz = gi[tid + NH];
      gin = gi[tid + 2 * NH];
    }
    // gh[j] = Whh[j,:] @ h  — W from VGPRs, h broadcast from LDS.
    float acc = 0.0f;
    const uint4* h4 = (const uint4*)h16p;
#pragma unroll
    for (int k = 0; k < 32; ++k) {
      uint4 hv = h4[k];
      acc = fdot2_(w[4 * k + 0], hv.x, acc);
      acc = fdot2_(w[4 * k + 1], hv.y, acc);
      acc = fdot2_(w[4 * k + 2], hv.z, acc);
      acc = fdot2_(w[4 * k + 3], hv.w, acc);
    }
    gh[tid] = acc;
    __syncthreads();
    if (tid < NH) {
      float r = sigmoidf_(gir + gh[tid] + br);
      float z = sigmoidf_(giz + gh[tid + NH] + bz);
      float n = tanhf(gin + r * (gh[tid + 2 * NH] + bn));
      hreg = (1.0f - z) * n + z * hreg;
      hmax = fmaxf(hmax, hreg);
      ((unsigned short*)h16p)[tid] = __half_as_ushort(__float2half_rn(hreg));
    }
    __syncthreads();
  }
  if (tid < NH) out[(size_t)b * (2 * NH) + (size_t)dir * NH + tid] = hmax;
}

// ---------------------------------------------------------------------------
extern "C" void kernel_launch(void* const* d_in, const int* in_sizes, int n_in,
                              void* d_out, int out_size, void* d_ws, size_t ws_size,
                              hipStream_t stream) {
  const int*   tokens = (const int*)d_in[0];
  const float* emb    = (const float*)d_in[1];
  const float* Wc     = (const float*)d_in[2];
  const float* bc     = (const float*)d_in[3];
  const float* Wih_f  = (const float*)d_in[4];
  const float* Whh_f  = (const float*)d_in[5];
  const float* bih_f  = (const float*)d_in[6];
  const float* bhh_f  = (const float*)d_in[7];
  const float* Wih_b  = (const float*)d_in[8];
  const float* Whh_b  = (const float*)d_in[9];
  const float* bih_b  = (const float*)d_in[10];
  const float* bhh_b  = (const float*)d_in[11];
  float* out = (float*)d_out;

  // Workspace (f32 units): P[V*C] | enc[B*L*C] | GI[2*B*L*3H] | Wh16[2*768*128]
  float* P   = (float*)d_ws;
  float* enc = P + (size_t)NV * NC;
  float* GI  = enc + (size_t)NB * NL * NC;
  unsigned int* Wh16 = (unsigned int*)(GI + (size_t)2 * NB * NL * G3);

  // 0) Pack Whh -> f16 pairs.
  conv_w_f16<<<dim3((G3 * (NH / 2) + 255) / 256), dim3(256), 0, stream>>>(
      Whh_f, Whh_b, Wh16);
  // 1) P = emb @ Wc^T   (V x C)
  gemm_bt_k128<<<dim3((NV + 63) / 64, NC / 128), dim3(256), 0, stream>>>(
      emb, Wc, nullptr, P, NV, NC);
  // 2) tree encode -> enc (B*L x C)
  tree_encode<<<dim3(NB * NL), dim3(128), 0, stream>>>(tokens, P, bc, enc);
  // 3) GI = enc @ Wih^T + bih (both directions)
  gemm_bt_k128<<<dim3(NB * NL / 64, G3 / 128), dim3(256), 0, stream>>>(
      enc, Wih_f, bih_f, GI, NB * NL, G3);
  gemm_bt_k128<<<dim3(NB * NL / 64, G3 / 128), dim3(256), 0, stream>>>(
      enc, Wih_b, bih_b, GI + (size_t)NB * NL * G3, NB * NL, G3);
  // 4) GRU scan, register-resident W.
  gru_scan_reg<<<dim3(64), dim3(768), 0, stream>>>(
      Wh16, GI, bhh_f, bhh_b, out);
}

// Round 3
// 324.344 us; speedup vs baseline: 8.9878x; 1.0955x over previous
//
#include <hip/hip_runtime.h>
#include <hip/hip_bf16.h>
#include <hip/hip_fp16.h>
#include <math.h>

// Problem constants: B=32, L=128, D=6, T=63, V=50000, E=C=128, H=256
#define NV 50000
#define NC 128
#define NH 256
#define NB 32
#define NL 128
#define NT 63
#define G3 768   // 3*H

typedef _Float16 half2_t __attribute__((ext_vector_type(2)));

__device__ __forceinline__ float sigmoidf_(float x) { return 1.0f / (1.0f + expf(-x)); }

__device__ __forceinline__ float fdot2_(unsigned int a, unsigned int b, float c) {
#if __has_builtin(__builtin_amdgcn_fdot2)
  return __builtin_amdgcn_fdot2(__builtin_bit_cast(half2_t, a),
                                __builtin_bit_cast(half2_t, b), c, false);
#else
  half2_t ah = __builtin_bit_cast(half2_t, a);
  half2_t bh = __builtin_bit_cast(half2_t, b);
  return fmaf((float)ah[0], (float)bh[0], fmaf((float)ah[1], (float)bh[1], c));
#endif
}

// ---------------------------------------------------------------------------
// C[m][n] = sum_k A[m][k]*B[n][k] (+bias), K=128. Single-output version (P).
// ---------------------------------------------------------------------------
__global__ __launch_bounds__(256) void gemm_bt_k128(
    const float* __restrict__ A, const float* __restrict__ Bm,
    const float* __restrict__ bias, float* __restrict__ Cm,
    int M, int N) {
  __shared__ __align__(16) float As[64 * 129];
  __shared__ __align__(16) float BsT[128 * 132];
  const int m0 = blockIdx.x * 64;
  const int n0 = blockIdx.y * 128;
  const int tid = threadIdx.x;

#pragma unroll
  for (int i = 0; i < 32; ++i) {
    int e = tid + i * 256;
    int r = e >> 7, k = e & 127;
    int m = m0 + r;
    As[r * 129 + k] = (m < M) ? A[(size_t)m * 128 + k] : 0.0f;
  }
#pragma unroll
  for (int i = 0; i < 64; ++i) {
    int e = tid + i * 256;
    int n = e >> 7, k = e & 127;
    BsT[k * 132 + n] = Bm[(size_t)(n0 + n) * 128 + k];
  }
  __syncthreads();

  const int tn = tid & 15;
  const int tm = tid >> 4;
  const int ml = tm * 4, nl = tn * 8;

  float acc[4][8];
#pragma unroll
  for (int i = 0; i < 4; ++i)
#pragma unroll
    for (int j = 0; j < 8; ++j) acc[i][j] = 0.0f;

#pragma unroll 4
  for (int k = 0; k < 128; ++k) {
    float a0 = As[(ml + 0) * 129 + k];
    float a1 = As[(ml + 1) * 129 + k];
    float a2 = As[(ml + 2) * 129 + k];
    float a3 = As[(ml + 3) * 129 + k];
    float4 b0 = *(const float4*)&BsT[k * 132 + nl];
    float4 b1 = *(const float4*)&BsT[k * 132 + nl + 4];
    const float bv[8] = {b0.x, b0.y, b0.z, b0.w, b1.x, b1.y, b1.z, b1.w};
#pragma unroll
    for (int j = 0; j < 8; ++j) {
      acc[0][j] = fmaf(a0, bv[j], acc[0][j]);
      acc[1][j] = fmaf(a1, bv[j], acc[1][j]);
      acc[2][j] = fmaf(a2, bv[j], acc[2][j]);
      acc[3][j] = fmaf(a3, bv[j], acc[3][j]);
    }
  }

  float bv[8];
#pragma unroll
  for (int j = 0; j < 8; ++j) bv[j] = bias ? bias[n0 + nl + j] : 0.0f;

#pragma unroll
  for (int i = 0; i < 4; ++i) {
    int m = m0 + ml + i;
    if (m < M) {
      float* crow = &Cm[(size_t)m * N + n0 + nl];
#pragma unroll
      for (int j = 0; j < 8; ++j) crow[j] = acc[i][j] + bv[j];
    }
  }
}

// ---------------------------------------------------------------------------
// Dual GEMM: blockIdx.z picks (B0,bias0,C0) or (B1,bias1,C1). For GI f/b.
// ---------------------------------------------------------------------------
__global__ __launch_bounds__(256) void gemm_bt_k128_dual(
    const float* __restrict__ A,
    const float* __restrict__ B0, const float* __restrict__ B1,
    const float* __restrict__ bias0, const float* __restrict__ bias1,
    float* __restrict__ C0, float* __restrict__ C1, int M, int N) {
  const float* __restrict__ Bm = blockIdx.z ? B1 : B0;
  const float* __restrict__ bias = blockIdx.z ? bias1 : bias0;
  float* __restrict__ Cm = blockIdx.z ? C1 : C0;

  __shared__ __align__(16) float As[64 * 129];
  __shared__ __align__(16) float BsT[128 * 132];
  const int m0 = blockIdx.x * 64;
  const int n0 = blockIdx.y * 128;
  const int tid = threadIdx.x;

#pragma unroll
  for (int i = 0; i < 32; ++i) {
    int e = tid + i * 256;
    int r = e >> 7, k = e & 127;
    int m = m0 + r;
    As[r * 129 + k] = (m < M) ? A[(size_t)m * 128 + k] : 0.0f;
  }
#pragma unroll
  for (int i = 0; i < 64; ++i) {
    int e = tid + i * 256;
    int n = e >> 7, k = e & 127;
    BsT[k * 132 + n] = Bm[(size_t)(n0 + n) * 128 + k];
  }
  __syncthreads();

  const int tn = tid & 15;
  const int tm = tid >> 4;
  const int ml = tm * 4, nl = tn * 8;

  float acc[4][8];
#pragma unroll
  for (int i = 0; i < 4; ++i)
#pragma unroll
    for (int j = 0; j < 8; ++j) acc[i][j] = 0.0f;

#pragma unroll 4
  for (int k = 0; k < 128; ++k) {
    float a0 = As[(ml + 0) * 129 + k];
    float a1 = As[(ml + 1) * 129 + k];
    float a2 = As[(ml + 2) * 129 + k];
    float a3 = As[(ml + 3) * 129 + k];
    float4 b0 = *(const float4*)&BsT[k * 132 + nl];
    float4 b1 = *(const float4*)&BsT[k * 132 + nl + 4];
    const float bv[8] = {b0.x, b0.y, b0.z, b0.w, b1.x, b1.y, b1.z, b1.w};
#pragma unroll
    for (int j = 0; j < 8; ++j) {
      acc[0][j] = fmaf(a0, bv[j], acc[0][j]);
      acc[1][j] = fmaf(a1, bv[j], acc[1][j]);
      acc[2][j] = fmaf(a2, bv[j], acc[2][j]);
      acc[3][j] = fmaf(a3, bv[j], acc[3][j]);
    }
  }

  float bv[8];
#pragma unroll
  for (int j = 0; j < 8; ++j) bv[j] = bias[n0 + nl + j];

#pragma unroll
  for (int i = 0; i < 4; ++i) {
    int m = m0 + ml + i;
    if (m < M) {
      float* crow = &Cm[(size_t)m * N + n0 + nl];
#pragma unroll
      for (int j = 0; j < 8; ++j) crow[j] = acc[i][j] + bv[j];
    }
  }
}

// ---------------------------------------------------------------------------
// Tree encode: per (b,l), heap-sum P[tok], + cnt*bc, max, relu.
// ---------------------------------------------------------------------------
__global__ __launch_bounds__(128) void tree_encode(
    const int* __restrict__ tokens, const float* __restrict__ P,
    const float* __restrict__ bc, float* __restrict__ enc) {
  __shared__ int toks[NT];
  const int blk = blockIdx.x;
  const int c = threadIdx.x;
  if (c < NT) toks[c] = tokens[(size_t)blk * NT + c];
  __syncthreads();

  float s[NT];
#pragma unroll
  for (int i = 0; i < NT; ++i) s[i] = P[(size_t)toks[i] * NC + c];
#pragma unroll
  for (int i = 30; i >= 0; --i) s[i] += s[2 * i + 1] + s[2 * i + 2];

  const float bcv = bc[c];
  float m = -1e30f;
#pragma unroll
  for (int i = 0; i < NT; ++i) {
    const float cnt = (i == 0) ? 63.0f
                    : (i < 3)  ? 31.0f
                    : (i < 7)  ? 15.0f
                    : (i < 15) ? 7.0f
                    : (i < 31) ? 3.0f
                               : 1.0f;
    m = fmaxf(m, s[i] + cnt * bcv);
  }
  enc[(size_t)blk * NC + c] = fmaxf(m, 0.0f);
}

// ---------------------------------------------------------------------------
// Pack Whh f32 [768][256] -> chunk-major packed-f16: Wpk[dir][kc][row] uint4
// (kc = 8-value chunk index, 32 chunks). Coalesced register fill in the scan.
// ---------------------------------------------------------------------------
__global__ __launch_bounds__(256) void conv_w_pack(
    const float* __restrict__ Wf, const float* __restrict__ Wb,
    uint4* __restrict__ out) {
  int i = blockIdx.x * 256 + threadIdx.x;  // [0, 2*32*768)
  if (i >= 2 * 32 * G3) return;
  int dir = i / (32 * G3);
  int rem = i - dir * 32 * G3;
  int kc = rem / G3;
  int row = rem - kc * G3;
  const float* __restrict__ W = dir ? Wb : Wf;
  const float4 a = *(const float4*)&W[(size_t)row * NH + kc * 8];
  const float4 b = *(const float4*)&W[(size_t)row * NH + kc * 8 + 4];
  __half2 p0 = __floats2half2_rn(a.x, a.y);
  __half2 p1 = __floats2half2_rn(a.z, a.w);
  __half2 p2 = __floats2half2_rn(b.x, b.y);
  __half2 p3 = __floats2half2_rn(b.z, b.w);
  uint4 o;
  o.x = *(unsigned int*)&p0; o.y = *(unsigned int*)&p1;
  o.z = *(unsigned int*)&p2; o.w = *(unsigned int*)&p3;
  out[i] = o;
}

// ---------------------------------------------------------------------------
// GRU scan v4. 64 blocks (dir,b) x 512 threads (8 waves, 2/SIMD).
// Thread = (channel c, k-half kh). Owns rows r/z/n of channel c over half of
// K: 48 uint4 = 192 VGPRs of f16 weights. Pair partials combined with
// shfl_xor(1) — no gh LDS exchange. h double-buffered in LDS -> ONE barrier
// per step. gi prefetched one step ahead.
// ---------------------------------------------------------------------------
__global__ __launch_bounds__(512, 2) void gru_scan_v4(
    const uint4* __restrict__ Wpk, const float* __restrict__ GI,
    const float* __restrict__ bhh_f, const float* __restrict__ bhh_b,
    float* __restrict__ out) {
  const int dir = blockIdx.x >> 5;
  const int b = blockIdx.x & 31;
  const int tid = threadIdx.x;
  const int c = tid >> 1;    // channel [0,256)
  const int kh = tid & 1;    // k-half: chunks [kh*16, kh*16+16)

  __shared__ __align__(16) uint4 hbuf[2][32];  // h as packed f16, double-buffered

  // One-time coalesced register fill of this thread's weight slices.
  const uint4* __restrict__ Wd = Wpk + (size_t)dir * 32 * G3;
  uint4 wr[16], wz[16], wn[16];
#pragma unroll
  for (int j = 0; j < 16; ++j) {
    const size_t base = (size_t)(kh * 16 + j) * G3 + c;
    wr[j] = Wd[base];
    wz[j] = Wd[base + NH];
    wn[j] = Wd[base + 2 * NH];
  }
  const float* __restrict__ bhh = dir ? bhh_b : bhh_f;
  const float br = bhh[c], bz = bhh[c + NH], bn = bhh[c + 2 * NH];
  if (tid < 32) ((uint4*)hbuf)[tid] = uint4{0u, 0u, 0u, 0u};

  const float* __restrict__ gi_base =
      GI + ((size_t)dir * NB * NL + (size_t)b * NL) * G3;
  float gir, giz, gin;
  {
    const float* g = gi_base + (size_t)(dir ? NL - 1 : 0) * G3;
    gir = g[c]; giz = g[c + NH]; gin = g[c + 2 * NH];
  }
  float hreg = 0.0f, hmax = -1e30f;
  __syncthreads();

  for (int st = 0; st < NL; ++st) {
    // Prefetch next step's gi (hidden under the dot phase).
    float girN, gizN, ginN;
    {
      const int stn = (st + 1 < NL) ? st + 1 : st;
      const int tn = dir ? (NL - 1 - stn) : stn;
      const float* g = gi_base + (size_t)tn * G3;
      girN = g[c]; gizN = g[c + NH]; ginN = g[c + 2 * NH];
    }
    // Half-dot over this thread's 16 chunks, 3 gate rows.
    const uint4* __restrict__ h4 = hbuf[st & 1] + kh * 16;
    float ar = 0.f, az = 0.f, an = 0.f;
#pragma unroll
    for (int j = 0; j < 16; ++j) {
      uint4 hv = h4[j];
      ar = fdot2_(wr[j].x, hv.x, ar); ar = fdot2_(wr[j].y, hv.y, ar);
      ar = fdot2_(wr[j].z, hv.z, ar); ar = fdot2_(wr[j].w, hv.w, ar);
      az = fdot2_(wz[j].x, hv.x, az); az = fdot2_(wz[j].y, hv.y, az);
      az = fdot2_(wz[j].z, hv.z, az); az = fdot2_(wz[j].w, hv.w, az);
      an = fdot2_(wn[j].x, hv.x, an); an = fdot2_(wn[j].y, hv.y, an);
      an = fdot2_(wn[j].z, hv.z, an); an = fdot2_(wn[j].w, hv.w, an);
    }
    // Combine k-halves within the lane pair.
    ar += __shfl_xor(ar, 1);
    az += __shfl_xor(az, 1);
    an += __shfl_xor(an, 1);
    // Gates (computed redundantly in both lanes of the pair).
    float r = sigmoidf_(gir + ar + br);
    float z = sigmoidf_(giz + az + bz);
    float n = tanhf(gin + r * (an + bn));
    hreg = (1.0f - z) * n + z * hreg;
    hmax = fmaxf(hmax, hreg);
    if (kh == 0) {
      ((unsigned short*)hbuf[(st + 1) & 1])[c] =
          __half_as_ushort(__float2half_rn(hreg));
    }
    __syncthreads();
    gir = girN; giz = gizN; gin = ginN;
  }
  if (kh == 0) out[(size_t)b * (2 * NH) + (size_t)dir * NH + c] = hmax;
}

// ---------------------------------------------------------------------------
extern "C" void kernel_launch(void* const* d_in, const int* in_sizes, int n_in,
                              void* d_out, int out_size, void* d_ws, size_t ws_size,
                              hipStream_t stream) {
  const int*   tokens = (const int*)d_in[0];
  const float* emb    = (const float*)d_in[1];
  const float* Wc     = (const float*)d_in[2];
  const float* bc     = (const float*)d_in[3];
  const float* Wih_f  = (const float*)d_in[4];
  const float* Whh_f  = (const float*)d_in[5];
  const float* bih_f  = (const float*)d_in[6];
  const float* bhh_f  = (const float*)d_in[7];
  const float* Wih_b  = (const float*)d_in[8];
  const float* Whh_b  = (const float*)d_in[9];
  const float* bih_b  = (const float*)d_in[10];
  const float* bhh_b  = (const float*)d_in[11];
  float* out = (float*)d_out;

  // Workspace: P[V*C] | enc[B*L*C] | GI[2*B*L*3H] | Wpk[2*32*768] uint4
  float* P   = (float*)d_ws;
  float* enc = P + (size_t)NV * NC;
  float* GI  = enc + (size_t)NB * NL * NC;
  uint4* Wpk = (uint4*)(GI + (size_t)2 * NB * NL * G3);

  // 0) Pack Whh -> chunk-major f16.
  conv_w_pack<<<dim3((2 * 32 * G3 + 255) / 256), dim3(256), 0, stream>>>(
      Whh_f, Whh_b, Wpk);
  // 1) P = emb @ Wc^T   (V x C)
  gemm_bt_k128<<<dim3((NV + 63) / 64, NC / 128), dim3(256), 0, stream>>>(
      emb, Wc, nullptr, P, NV, NC);
  // 2) tree encode -> enc (B*L x C)
  tree_encode<<<dim3(NB * NL), dim3(128), 0, stream>>>(tokens, P, bc, enc);
  // 3) GI f+b in one launch (blockIdx.z = dir)
  gemm_bt_k128_dual<<<dim3(NB * NL / 64, G3 / 128, 2), dim3(256), 0, stream>>>(
      enc, Wih_f, Wih_b, bih_f, bih_b,
      GI, GI + (size_t)NB * NL * G3, NB * NL, G3);
  // 4) GRU scan v4.
  gru_scan_v4<<<dim3(64), dim3(512), 0, stream>>>(
      Wpk, GI, bhh_f, bhh_b, out);
}

// Round 4
// 323.174 us; speedup vs baseline: 9.0204x; 1.0036x over previous
//
#include <hip/hip_runtime.h>
#include <hip/hip_bf16.h>
#include <hip/hip_fp16.h>
#include <math.h>

// Problem constants: B=32, L=128, D=6, T=63, V=50000, E=C=128, H=256
#define NV 50000
#define NC 128
#define NH 256
#define NB 32
#define NL 128
#define NT 63
#define G3 768   // 3*H

typedef _Float16 half2_t __attribute__((ext_vector_type(2)));

__device__ __forceinline__ float sigmoidf_(float x) { return 1.0f / (1.0f + expf(-x)); }

__device__ __forceinline__ float fdot2_(unsigned int a, unsigned int b, float c) {
#if __has_builtin(__builtin_amdgcn_fdot2)
  return __builtin_amdgcn_fdot2(__builtin_bit_cast(half2_t, a),
                                __builtin_bit_cast(half2_t, b), c, false);
#else
  half2_t ah = __builtin_bit_cast(half2_t, a);
  half2_t bh = __builtin_bit_cast(half2_t, b);
  return fmaf((float)ah[0], (float)bh[0], fmaf((float)ah[1], (float)bh[1], c));
#endif
}

// quad_perm XOR-add via DPP (VALU only, no LDS pipe).
__device__ __forceinline__ float dpp_xor1_add(float v) {
  int x = __builtin_amdgcn_update_dpp(0, __builtin_bit_cast(int, v),
                                      0xB1 /*[1,0,3,2]*/, 0xF, 0xF, true);
  return v + __builtin_bit_cast(float, x);
}
__device__ __forceinline__ float dpp_xor2_add(float v) {
  int x = __builtin_amdgcn_update_dpp(0, __builtin_bit_cast(int, v),
                                      0x4E /*[2,3,0,1]*/, 0xF, 0xF, true);
  return v + __builtin_bit_cast(float, x);
}

// ---------------------------------------------------------------------------
// C[m][n] = sum_k A[m][k]*B[n][k] (+bias), K=128. B staged in two k-halves
// to keep LDS at 67KB -> 2 blocks/CU.
// ---------------------------------------------------------------------------
__global__ __launch_bounds__(256) void gemm_bt_k128(
    const float* __restrict__ A, const float* __restrict__ Bm,
    const float* __restrict__ bias, float* __restrict__ Cm,
    int M, int N) {
  __shared__ __align__(16) float As[64 * 129];
  __shared__ __align__(16) float BsT[64 * 132];  // [kk][n], one k-half
  const int m0 = blockIdx.x * 64;
  const int n0 = blockIdx.y * 128;
  const int tid = threadIdx.x;

#pragma unroll
  for (int i = 0; i < 32; ++i) {
    int e = tid + i * 256;
    int r = e >> 7, k = e & 127;
    int m = m0 + r;
    As[r * 129 + k] = (m < M) ? A[(size_t)m * 128 + k] : 0.0f;
  }

  const int tn = tid & 15;
  const int tm = tid >> 4;
  const int ml = tm * 4, nl = tn * 8;

  float acc[4][8];
#pragma unroll
  for (int i = 0; i < 4; ++i)
#pragma unroll
    for (int j = 0; j < 8; ++j) acc[i][j] = 0.0f;

#pragma unroll
  for (int h = 0; h < 2; ++h) {
    if (h) __syncthreads();
#pragma unroll
    for (int i = 0; i < 32; ++i) {
      int e = tid + i * 256;
      int n = e >> 6, kk = e & 63;
      BsT[kk * 132 + n] = Bm[(size_t)(n0 + n) * 128 + h * 64 + kk];
    }
    __syncthreads();
#pragma unroll 4
    for (int kk = 0; kk < 64; ++kk) {
      const int k = h * 64 + kk;
      float a0 = As[(ml + 0) * 129 + k];
      float a1 = As[(ml + 1) * 129 + k];
      float a2 = As[(ml + 2) * 129 + k];
      float a3 = As[(ml + 3) * 129 + k];
      float4 b0 = *(const float4*)&BsT[kk * 132 + nl];
      float4 b1 = *(const float4*)&BsT[kk * 132 + nl + 4];
      const float bv[8] = {b0.x, b0.y, b0.z, b0.w, b1.x, b1.y, b1.z, b1.w};
#pragma unroll
      for (int j = 0; j < 8; ++j) {
        acc[0][j] = fmaf(a0, bv[j], acc[0][j]);
        acc[1][j] = fmaf(a1, bv[j], acc[1][j]);
        acc[2][j] = fmaf(a2, bv[j], acc[2][j]);
        acc[3][j] = fmaf(a3, bv[j], acc[3][j]);
      }
    }
  }

  float bv[8];
#pragma unroll
  for (int j = 0; j < 8; ++j) bv[j] = bias ? bias[n0 + nl + j] : 0.0f;

#pragma unroll
  for (int i = 0; i < 4; ++i) {
    int m = m0 + ml + i;
    if (m < M) {
      float* crow = &Cm[(size_t)m * N + n0 + nl];
#pragma unroll
      for (int j = 0; j < 8; ++j) crow[j] = acc[i][j] + bv[j];
    }
  }
}

// ---------------------------------------------------------------------------
// Dual GEMM: blockIdx.z picks f/b weight+bias+output. Same k-split staging.
// ---------------------------------------------------------------------------
__global__ __launch_bounds__(256) void gemm_bt_k128_dual(
    const float* __restrict__ A,
    const float* __restrict__ B0, const float* __restrict__ B1,
    const float* __restrict__ bias0, const float* __restrict__ bias1,
    float* __restrict__ C0, float* __restrict__ C1, int M, int N) {
  const float* __restrict__ Bm = blockIdx.z ? B1 : B0;
  const float* __restrict__ bias = blockIdx.z ? bias1 : bias0;
  float* __restrict__ Cm = blockIdx.z ? C1 : C0;

  __shared__ __align__(16) float As[64 * 129];
  __shared__ __align__(16) float BsT[64 * 132];
  const int m0 = blockIdx.x * 64;
  const int n0 = blockIdx.y * 128;
  const int tid = threadIdx.x;

#pragma unroll
  for (int i = 0; i < 32; ++i) {
    int e = tid + i * 256;
    int r = e >> 7, k = e & 127;
    int m = m0 + r;
    As[r * 129 + k] = (m < M) ? A[(size_t)m * 128 + k] : 0.0f;
  }

  const int tn = tid & 15;
  const int tm = tid >> 4;
  const int ml = tm * 4, nl = tn * 8;

  float acc[4][8];
#pragma unroll
  for (int i = 0; i < 4; ++i)
#pragma unroll
    for (int j = 0; j < 8; ++j) acc[i][j] = 0.0f;

#pragma unroll
  for (int h = 0; h < 2; ++h) {
    if (h) __syncthreads();
#pragma unroll
    for (int i = 0; i < 32; ++i) {
      int e = tid + i * 256;
      int n = e >> 6, kk = e & 63;
      BsT[kk * 132 + n] = Bm[(size_t)(n0 + n) * 128 + h * 64 + kk];
    }
    __syncthreads();
#pragma unroll 4
    for (int kk = 0; kk < 64; ++kk) {
      const int k = h * 64 + kk;
      float a0 = As[(ml + 0) * 129 + k];
      float a1 = As[(ml + 1) * 129 + k];
      float a2 = As[(ml + 2) * 129 + k];
      float a3 = As[(ml + 3) * 129 + k];
      float4 b0 = *(const float4*)&BsT[kk * 132 + nl];
      float4 b1 = *(const float4*)&BsT[kk * 132 + nl + 4];
      const float bv[8] = {b0.x, b0.y, b0.z, b0.w, b1.x, b1.y, b1.z, b1.w};
#pragma unroll
      for (int j = 0; j < 8; ++j) {
        acc[0][j] = fmaf(a0, bv[j], acc[0][j]);
        acc[1][j] = fmaf(a1, bv[j], acc[1][j]);
        acc[2][j] = fmaf(a2, bv[j], acc[2][j]);
        acc[3][j] = fmaf(a3, bv[j], acc[3][j]);
      }
    }
  }

  float bv[8];
#pragma unroll
  for (int j = 0; j < 8; ++j) bv[j] = bias[n0 + nl + j];

#pragma unroll
  for (int i = 0; i < 4; ++i) {
    int m = m0 + ml + i;
    if (m < M) {
      float* crow = &Cm[(size_t)m * N + n0 + nl];
#pragma unroll
      for (int j = 0; j < 8; ++j) crow[j] = acc[i][j] + bv[j];
    }
  }
}

// ---------------------------------------------------------------------------
// Tree encode: per (b,l), heap-sum P[tok], + cnt*bc, max, relu.
// ---------------------------------------------------------------------------
__global__ __launch_bounds__(128) void tree_encode(
    const int* __restrict__ tokens, const float* __restrict__ P,
    const float* __restrict__ bc, float* __restrict__ enc) {
  __shared__ int toks[NT];
  const int blk = blockIdx.x;
  const int c = threadIdx.x;
  if (c < NT) toks[c] = tokens[(size_t)blk * NT + c];
  __syncthreads();

  float s[NT];
#pragma unroll
  for (int i = 0; i < NT; ++i) s[i] = P[(size_t)toks[i] * NC + c];
#pragma unroll
  for (int i = 30; i >= 0; --i) s[i] += s[2 * i + 1] + s[2 * i + 2];

  const float bcv = bc[c];
  float m = -1e30f;
#pragma unroll
  for (int i = 0; i < NT; ++i) {
    const float cnt = (i == 0) ? 63.0f
                    : (i < 3)  ? 31.0f
                    : (i < 7)  ? 15.0f
                    : (i < 15) ? 7.0f
                    : (i < 31) ? 3.0f
                               : 1.0f;
    m = fmaxf(m, s[i] + cnt * bcv);
  }
  enc[(size_t)blk * NC + c] = fmaxf(m, 0.0f);
}

// ---------------------------------------------------------------------------
// Pack Whh f32 [768][256] -> per-thread-coalesced f16 uint4:
// out[((dir*48 + jj)*128 + g)*4 + q], jj = rowSel*8 + j, rowSel in [0,6):
//   row = (rowSel%3)*256 + (rowSel/3)*128 + g, k-chunk kc = q*8 + j.
// In the scan: thread (g,q) does  w[jj] = Wd[jj*512 + tid]  (fully coalesced).
// ---------------------------------------------------------------------------
__global__ __launch_bounds__(256) void conv_w_pack(
    const float* __restrict__ Wf, const float* __restrict__ Wb,
    uint4* __restrict__ out) {
  int i = blockIdx.x * 256 + threadIdx.x;  // [0, 2*48*512)
  if (i >= 2 * 48 * 512) return;
  const int dir = i / (48 * 512);
  int rem = i - dir * (48 * 512);
  const int jj = rem >> 9;           // [0,48)
  const int gq = rem & 511;
  const int g = gq >> 2;             // [0,128)
  const int q = gq & 3;              // [0,4)
  const int rowSel = jj >> 3;        // [0,6)
  const int j = jj & 7;              // [0,8)
  const int row = (rowSel % 3) * 256 + (rowSel / 3) * 128 + g;
  const int kc = q * 8 + j;          // 8-value chunk in [0,32)
  const float* __restrict__ W = dir ? Wb : Wf;
  const float4 a = *(const float4*)&W[(size_t)row * NH + kc * 8];
  const float4 b = *(const float4*)&W[(size_t)row * NH + kc * 8 + 4];
  __half2 p0 = __floats2half2_rn(a.x, a.y);
  __half2 p1 = __floats2half2_rn(a.z, a.w);
  __half2 p2 = __floats2half2_rn(b.x, b.y);
  __half2 p3 = __floats2half2_rn(b.z, b.w);
  uint4 o;
  o.x = *(unsigned int*)&p0; o.y = *(unsigned int*)&p1;
  o.z = *(unsigned int*)&p2; o.w = *(unsigned int*)&p3;
  out[i] = o;
}

// ---------------------------------------------------------------------------
// GRU scan v5. 64 blocks (dir,b) x 512 threads (8 waves, 2/SIMD).
// Quad of lanes = (channel pair {g, g+128}) x (k-quarter q). Each thread:
// 6 gate-rows over 64 k -> 48 uint4 f16 weights in regs. Quad partials
// combined via DPP quad_perm butterflies (no LDS pipe). h stored as 4 chunks
// at 144B stride -> conflict-free quad broadcast. One barrier/step.
// ---------------------------------------------------------------------------
__global__ __launch_bounds__(512, 2) void gru_scan_v5(
    const uint4* __restrict__ Wpk, const float* __restrict__ GI,
    const float* __restrict__ bhh_f, const float* __restrict__ bhh_b,
    float* __restrict__ out) {
  const int dir = blockIdx.x >> 5;
  const int b = blockIdx.x & 31;
  const int tid = threadIdx.x;
  const int g = tid >> 2;     // channel-pair group [0,128)
  const int q = tid & 3;      // k-quarter

  // h double-buffered: 4 chunks of 64 f16 (128B) at stride 144B.
  __shared__ __align__(16) unsigned short hbuf[2][288];  // 288 ushort = 576B

  // Coalesced one-time weight fill: 48 x global_load_dwordx4.
  const uint4* __restrict__ Wd = Wpk + (size_t)dir * 48 * 512;
  uint4 w[48];
#pragma unroll
  for (int jj = 0; jj < 48; ++jj) w[jj] = Wd[(size_t)jj * 512 + tid];

  const bool owner = ((q & 1) == 0);          // lanes 0,2 compute gates
  const int c = g + (q >> 1) * 128;           // owned channel (lanes 0,2)
  const float* __restrict__ bhh = dir ? bhh_b : bhh_f;
  float br = 0.f, bz = 0.f, bn = 0.f;
  if (owner) {
    br = bhh[c]; bz = bhh[c + NH]; bn = bhh[c + 2 * NH];
  }
  if (tid < 144) ((unsigned int*)&hbuf[0][0])[tid] = 0u;

  const float* __restrict__ gi_base =
      GI + ((size_t)dir * NB * NL + (size_t)b * NL) * G3;
  float gir = 0.f, giz = 0.f, gin = 0.f;
  if (owner) {
    const float* gi = gi_base + (size_t)(dir ? NL - 1 : 0) * G3;
    gir = gi[c]; giz = gi[c + NH]; gin = gi[c + 2 * NH];
  }
  float hreg = 0.0f, hmax = -1e30f;
  __syncthreads();

  for (int st = 0; st < NL; ++st) {
    // Prefetch next step's gi (hidden under dots).
    float girN = 0.f, gizN = 0.f, ginN = 0.f;
    if (owner) {
      const int stn = (st + 1 < NL) ? st + 1 : st;
      const int t = dir ? (NL - 1 - stn) : stn;
      const float* gi = gi_base + (size_t)t * G3;
      girN = gi[c]; gizN = gi[c + NH]; ginN = gi[c + 2 * NH];
    }
    // Quarter-dots: 6 rows x 64 k. h chunk q at byte offset q*144.
    const uint4* __restrict__ hp =
        (const uint4*)((const char*)&hbuf[st & 1][0] + q * 144);
    float a0 = 0.f, a1 = 0.f, a2 = 0.f, a3 = 0.f, a4 = 0.f, a5 = 0.f;
#pragma unroll
    for (int j = 0; j < 8; ++j) {
      uint4 hv = hp[j];
      a0 = fdot2_(w[j].x, hv.x, a0);      a0 = fdot2_(w[j].y, hv.y, a0);
      a0 = fdot2_(w[j].z, hv.z, a0);      a0 = fdot2_(w[j].w, hv.w, a0);
      a1 = fdot2_(w[8+j].x, hv.x, a1);    a1 = fdot2_(w[8+j].y, hv.y, a1);
      a1 = fdot2_(w[8+j].z, hv.z, a1);    a1 = fdot2_(w[8+j].w, hv.w, a1);
      a2 = fdot2_(w[16+j].x, hv.x, a2);   a2 = fdot2_(w[16+j].y, hv.y, a2);
      a2 = fdot2_(w[16+j].z, hv.z, a2);   a2 = fdot2_(w[16+j].w, hv.w, a2);
      a3 = fdot2_(w[24+j].x, hv.x, a3);   a3 = fdot2_(w[24+j].y, hv.y, a3);
      a3 = fdot2_(w[24+j].z, hv.z, a3);   a3 = fdot2_(w[24+j].w, hv.w, a3);
      a4 = fdot2_(w[32+j].x, hv.x, a4);   a4 = fdot2_(w[32+j].y, hv.y, a4);
      a4 = fdot2_(w[32+j].z, hv.z, a4);   a4 = fdot2_(w[32+j].w, hv.w, a4);
      a5 = fdot2_(w[40+j].x, hv.x, a5);   a5 = fdot2_(w[40+j].y, hv.y, a5);
      a5 = fdot2_(w[40+j].z, hv.z, a5);   a5 = fdot2_(w[40+j].w, hv.w, a5);
    }
    // Quad butterfly (DPP, VALU-only): all 4 lanes get full sums.
    a0 = dpp_xor2_add(dpp_xor1_add(a0));
    a1 = dpp_xor2_add(dpp_xor1_add(a1));
    a2 = dpp_xor2_add(dpp_xor1_add(a2));
    a3 = dpp_xor2_add(dpp_xor1_add(a3));
    a4 = dpp_xor2_add(dpp_xor1_add(a4));
    a5 = dpp_xor2_add(dpp_xor1_add(a5));
    // Gates in owner lanes (0 -> channel g, 2 -> channel g+128).
    if (owner) {
      const float sr = (q >> 1) ? a3 : a0;
      const float sz = (q >> 1) ? a4 : a1;
      const float sn = (q >> 1) ? a5 : a2;
      float r = sigmoidf_(gir + sr + br);
      float z = sigmoidf_(giz + sz + bz);
      float n = tanhf(gin + r * (sn + bn));
      hreg = (1.0f - z) * n + z * hreg;
      hmax = fmaxf(hmax, hreg);
      hbuf[(st + 1) & 1][(c >> 6) * 72 + (c & 63)] =
          __half_as_ushort(__float2half_rn(hreg));
    }
    __syncthreads();
    gir = girN; giz = gizN; gin = ginN;
  }
  if (owner) out[(size_t)b * (2 * NH) + (size_t)dir * NH + c] = hmax;
}

// ---------------------------------------------------------------------------
extern "C" void kernel_launch(void* const* d_in, const int* in_sizes, int n_in,
                              void* d_out, int out_size, void* d_ws, size_t ws_size,
                              hipStream_t stream) {
  const int*   tokens = (const int*)d_in[0];
  const float* emb    = (const float*)d_in[1];
  const float* Wc     = (const float*)d_in[2];
  const float* bc     = (const float*)d_in[3];
  const float* Wih_f  = (const float*)d_in[4];
  const float* Whh_f  = (const float*)d_in[5];
  const float* bih_f  = (const float*)d_in[6];
  const float* bhh_f  = (const float*)d_in[7];
  const float* Wih_b  = (const float*)d_in[8];
  const float* Whh_b  = (const float*)d_in[9];
  const float* bih_b  = (const float*)d_in[10];
  const float* bhh_b  = (const float*)d_in[11];
  float* out = (float*)d_out;

  // Workspace: P[V*C] | enc[B*L*C] | GI[2*B*L*3H] | Wpk[2*48*512] uint4
  float* P   = (float*)d_ws;
  float* enc = P + (size_t)NV * NC;
  float* GI  = enc + (size_t)NB * NL * NC;
  uint4* Wpk = (uint4*)(GI + (size_t)2 * NB * NL * G3);

  // 0) Pack Whh -> per-thread coalesced f16.
  conv_w_pack<<<dim3((2 * 48 * 512 + 255) / 256), dim3(256), 0, stream>>>(
      Whh_f, Whh_b, Wpk);
  // 1) P = emb @ Wc^T   (V x C)
  gemm_bt_k128<<<dim3((NV + 63) / 64, NC / 128), dim3(256), 0, stream>>>(
      emb, Wc, nullptr, P, NV, NC);
  // 2) tree encode -> enc (B*L x C)
  tree_encode<<<dim3(NB * NL), dim3(128), 0, stream>>>(tokens, P, bc, enc);
  // 3) GI f+b in one launch (blockIdx.z = dir)
  gemm_bt_k128_dual<<<dim3(NB * NL / 64, G3 / 128, 2), dim3(256), 0, stream>>>(
      enc, Wih_f, Wih_b, bih_f, bih_b,
      GI, GI + (size_t)NB * NL * G3, NB * NL, G3);
  // 4) GRU scan v5.
  gru_scan_v5<<<dim3(64), dim3(512), 0, stream>>>(
      Wpk, GI, bhh_f, bhh_b, out);
}